// Round 16
// baseline (68.211 us; speedup 1.0000x reference)
//
#include <hip/hip_runtime.h>

typedef unsigned short u16;
typedef unsigned int u32;
typedef __attribute__((ext_vector_type(8))) __bf16 bf16x8;
typedef __attribute__((ext_vector_type(4))) float f32x4;
typedef __attribute__((ext_vector_type(4))) u32 u32x4;

__device__ __forceinline__ u16 f2bf(float f) {
  u32 u = __builtin_bit_cast(u32, f);
  u = (u + 0x7fffu + ((u >> 16) & 1u)) >> 16;
  return (u16)u;
}
__device__ __forceinline__ float bf2f(u16 h) {
  return __builtin_bit_cast(float, (u32)h << 16);
}
// async global->LDS, 16B per lane; lds dest is wave-uniform base + lane*16
__device__ __forceinline__ void async16(const void* g, void* l) {
  __builtin_amdgcn_global_load_lds((const __attribute__((address_space(1))) u32*)g,
                                   (__attribute__((address_space(3))) u32*)l, 16, 0, 0);
}
template<int N> __device__ __forceinline__ void wait_vm() {
  if constexpr (N == 0) asm volatile("s_waitcnt vmcnt(0)" ::: "memory");
  else if constexpr (N == 2) asm volatile("s_waitcnt vmcnt(2)" ::: "memory");
  else if constexpr (N == 3) asm volatile("s_waitcnt vmcnt(3)" ::: "memory");
  else if constexpr (N == 4) asm volatile("s_waitcnt vmcnt(4)" ::: "memory");
  else if constexpr (N == 5) asm volatile("s_waitcnt vmcnt(5)" ::: "memory");
}

// ---------------- merged prep: x->bf16 | trig table | weight transpose+bf16 ----------------
__global__ __launch_bounds__(256) void prep_k(const float* __restrict__ x,
    const float* __restrict__ wq, const float* __restrict__ wk,
    const float* __restrict__ wv, const float* __restrict__ wo,
    u16* __restrict__ xb, u16* __restrict__ wqt, u16* __restrict__ wkt,
    u16* __restrict__ wvt, u16* __restrict__ wot, float* __restrict__ trig) {
  __shared__ float tile[32][33];
  int b = blockIdx.x, t = threadIdx.x;
  if (b < 1024) {            // conv x: 2048*1024 elems, 8/thread
    int i = (b * 256 + t) * 8;
    u16 tmp[8];
    #pragma unroll
    for (int j = 0; j < 8; ++j) tmp[j] = f2bf(x[i + j]);
    *(u32x4*)(&xb[i]) = *(u32x4*)tmp;
  } else if (b < 1280) {     // trig: idx = l*32+j over 2048*32
    int idx = (b - 1024) * 256 + t;
    int l = idx >> 5, j = idx & 31;
    float invf = powf(10000.0f, -(float)j * (1.0f / 32.0f));
    float ang = (float)l * invf;
    trig[idx * 2 + 0] = cosf(ang);
    trig[idx * 2 + 1] = sinf(ang);
  } else {                   // weight transpose: 4 mats x 1024 tiles of 32x32
    int bb = b - 1280;
    int z = bb >> 10, tt = bb & 1023;
    const float* w = z == 0 ? wq : z == 1 ? wk : z == 2 ? wv : wo;
    u16* o = z == 0 ? wqt : z == 1 ? wkt : z == 2 ? wvt : wot;
    int tx = t & 31, ty = t >> 5;
    int n0 = (tt & 31) * 32, k0 = (tt >> 5) * 32;
    #pragma unroll
    for (int j = 0; j < 4; ++j) tile[ty + j*8][tx] = w[(size_t)(k0 + ty + j*8) * 1024 + n0 + tx];
    __syncthreads();
    #pragma unroll
    for (int j = 0; j < 4; ++j) o[(size_t)(n0 + ty + j*8) * 1024 + k0 + tx] = f2bf(tile[tx][ty + j*8]);
  }
}

// ---------------- qkv GEMM: 128x96 tile, BK=64, 6 waves of 64x32 (2x3), 512 blocks ----
// Wave tile 64x32: 6 ds_reads / 8 MFMA per ks (vs 1:1 for 32x32) — cuts LDS reads/FLOP.
// Same 128x96 block tile / grid / swizzle / traffic as R11 best.
__global__ __launch_bounds__(384) void gemm_qkv(
    const u16* __restrict__ A, const u16* __restrict__ B,
    u16* __restrict__ Cq, u16* __restrict__ Ck, u16* __restrict__ Cv,
    const float* __restrict__ trig)
{
  constexpr int BM = 128, BN = 96, K = 1024, NT = 16;
  constexpr int LDSZ = (BM + BN) * 64;        // 28KB per buffer
  __shared__ __align__(16) u16 lds[2][LDSZ];
  const int t = threadIdx.x, lane = t & 63, w = t >> 6;   // w in 0..5
  const int la = lane & 15, lb = lane >> 4;
  const int hw = blockIdx.x;
  const int xcd = hw & 7, q = hw >> 3;
  const int bx = (xcd & 3) * 8 + (q & 7);     // 32 bx
  const int by = (xcd >> 2) * 8 + (q >> 3);   // 16 by
  const int brow = by * BM, bn0 = bx * BN;
  const u16* Bp = B + (size_t)bn0 * K;
  const int wrow = (w / 3) * 64, wcol = (w % 3) * 32;  // wave tile 64x32 (2 rows x 3 cols)
  f32x4 acc[4][2];
  #pragma unroll
  for (int m = 0; m < 4; ++m)
    #pragma unroll
    for (int n = 0; n < 2; ++n) acc[m][n] = (f32x4){0.f, 0.f, 0.f, 0.f};
  const int srow8 = lane >> 3;                // row within 8-row chunk
  const int sw8 = (((lane & 7) ^ srow8) << 3);

  // staging: A = 16 chunks (8r x 64c = 1KB), B = 12 chunks; 28 chunks over 6 waves:
  // wave w takes chunks {w, w+6, w+12, w+18}; waves 0..3 also {w+24}.
  auto stageChunk = [&](int buf, int k0, int c) {
    if (c < 16) async16(&A[(size_t)(brow + c * 8 + srow8) * K + k0 + sw8], &lds[buf][c * 512]);
    else        async16(&Bp[(size_t)((c - 16) * 8 + srow8) * K + k0 + sw8], &lds[buf][BM * 64 + (c - 16) * 512]);
  };
  auto stage = [&](int buf, int kt) {
    const int k0 = kt * 64;
    stageChunk(buf, k0, w);
    stageChunk(buf, k0, w + 6);
    stageChunk(buf, k0, w + 12);
    stageChunk(buf, k0, w + 18);
    if (w < 4) stageChunk(buf, k0, w + 24);
  };
  auto wait_stage = [&](bool last) {   // keep 1 stage (5 or 4 loads) in flight
    if (last) { wait_vm<0>(); }
    else if (w < 4) { wait_vm<5>(); }
    else { wait_vm<4>(); }
  };
  auto compute = [&](int buf) {
    __builtin_amdgcn_s_setprio(1);
    #pragma unroll
    for (int ks = 0; ks < 2; ++ks) {
      bf16x8 af[4], bff[2];
      const int slot = ks * 4 + lb;
      #pragma unroll
      for (int m = 0; m < 4; ++m) {
        int row = wrow + m * 16 + la;
        af[m] = __builtin_bit_cast(bf16x8,
            *(const u32x4*)(&lds[buf][row * 64 + ((slot ^ (row & 7)) << 3)]));
      }
      #pragma unroll
      for (int n = 0; n < 2; ++n) {
        int row = wcol + n * 16 + la;
        bff[n] = __builtin_bit_cast(bf16x8,
            *(const u32x4*)(&lds[buf][BM * 64 + row * 64 + ((slot ^ (row & 7)) << 3)]));
      }
      #pragma unroll
      for (int m = 0; m < 4; ++m)
        #pragma unroll
        for (int n = 0; n < 2; ++n)
          acc[m][n] = __builtin_amdgcn_mfma_f32_16x16x32_bf16(af[m], bff[n], acc[m][n], 0, 0, 0);
    }
    __builtin_amdgcn_s_setprio(0);
  };

  stage(0, 0);
  stage(1, 1);
  for (int kt = 0; kt < NT; ++kt) {
    wait_stage(kt == NT - 1);            // stage kt landed; kt+1 stays in flight
    __builtin_amdgcn_s_barrier();
    compute(kt & 1);
    __builtin_amdgcn_s_barrier();        // all waves done reading buf kt&1
    if (kt + 2 < NT) stage(kt & 1, kt + 2);
  }

  // C/D layout: row = (lane>>4)*4 + j, col = lane&15  [m89]; per-n z select
  #pragma unroll
  for (int m = 0; m < 4; ++m) {
    #pragma unroll
    for (int n = 0; n < 2; ++n) {
      int gcol = bn0 + wcol + n * 16 + la;
      int z = gcol >> 10, colz = gcol & 1023;
      u16* C = z == 0 ? Cq : z == 1 ? Ck : Cv;
      bool do_rope = z < 2;
      int jj = (colz & 63) >> 1;
      bool odd = colz & 1;
      #pragma unroll
      for (int j = 0; j < 4; ++j) {
        int r = brow + wrow + m * 16 + lb * 4 + j;
        float v = acc[m][n][j];
        float p = __shfl_xor(v, 1);   // pair partner (col ^ 1) — uniform exec
        if (do_rope) {
          float2 t2 = *(const float2*)(&trig[((size_t)r * 32 + jj) * 2]);
          v = odd ? (p * t2.y + v * t2.x) : (v * t2.x - p * t2.y);
          v = fmaxf(v, 0.f);
        }
        C[(size_t)r * 1024 + colz] = f2bf(v);
      }
    }
  }
}

// ---------------- wo GEMM: 128x32 tile, BK=64, 8 waves (512 thr), 2-buf counted-vmcnt ----
__global__ __launch_bounds__(512) void gemm_wo(
    const u16* __restrict__ A, const u16* __restrict__ B, float* __restrict__ Cf)
{
  constexpr int BM = 128, BN = 32, K = 1024, NT = 16;
  constexpr int LDSZ = (BM + BN) * 64;        // 20KB per buffer
  __shared__ __align__(16) u16 lds[2][LDSZ];
  const int t = threadIdx.x, lane = t & 63, w = t >> 6;   // w in 0..7
  const int la = lane & 15, lb = lane >> 4;
  const int hw = blockIdx.x;
  const int xcd = hw & 7, q = hw >> 3;        // q in [0,64)
  const int bx = (xcd & 1) * 16 + (q & 15);   // 32 bx over N=1024
  const int by = (xcd >> 1) * 4 + (q >> 4);   // 16 by over M=2048
  const int brow = by * BM, bn0 = bx * BN;
  const u16* Bp = B + (size_t)bn0 * K;
  const int wr = (w >> 1) * 32, wc = (w & 1) * 16;   // wave tile 32x16 (4x2 partition)
  f32x4 acc[2][1];
  #pragma unroll
  for (int m = 0; m < 2; ++m) acc[m][0] = (f32x4){0.f, 0.f, 0.f, 0.f};
  const int srow8 = lane >> 3;
  const int sw8 = (((lane & 7) ^ srow8) << 3);

  // staging: A = 16 chunks, B = 4 chunks. wave w: A {w, w+8}; waves 0-3: B {w}.
  auto stage = [&](int buf, int kt) {
    const int k0 = kt * 64;
    async16(&A[(size_t)(brow + w * 8 + srow8) * K + k0 + sw8], &lds[buf][w * 512]);
    async16(&A[(size_t)(brow + (w + 8) * 8 + srow8) * K + k0 + sw8], &lds[buf][(w + 8) * 512]);
    if (w < 4)
      async16(&Bp[(size_t)(w * 8 + srow8) * K + k0 + sw8], &lds[buf][BM * 64 + w * 512]);
  };
  auto wait_stage = [&](bool last) {
    if (last) { wait_vm<0>(); }
    else if (w < 4) { wait_vm<3>(); }
    else { wait_vm<2>(); }
  };
  auto compute = [&](int buf) {
    __builtin_amdgcn_s_setprio(1);
    #pragma unroll
    for (int ks = 0; ks < 2; ++ks) {
      bf16x8 af[2], bf1;
      const int slot = ks * 4 + lb;
      #pragma unroll
      for (int m = 0; m < 2; ++m) {
        int row = wr + m * 16 + la;
        af[m] = __builtin_bit_cast(bf16x8,
            *(const u32x4*)(&lds[buf][row * 64 + ((slot ^ (row & 7)) << 3)]));
      }
      {
        int row = wc + la;
        bf1 = __builtin_bit_cast(bf16x8,
            *(const u32x4*)(&lds[buf][BM * 64 + row * 64 + ((slot ^ (row & 7)) << 3)]));
      }
      #pragma unroll
      for (int m = 0; m < 2; ++m)
        acc[m][0] = __builtin_amdgcn_mfma_f32_16x16x32_bf16(af[m], bf1, acc[m][0], 0, 0, 0);
    }
    __builtin_amdgcn_s_setprio(0);
  };

  stage(0, 0);
  stage(1, 1);
  for (int kt = 0; kt < NT; ++kt) {
    wait_stage(kt == NT - 1);
    __builtin_amdgcn_s_barrier();
    compute(kt & 1);
    __builtin_amdgcn_s_barrier();
    if (kt + 2 < NT) stage(kt & 1, kt + 2);
  }

  #pragma unroll
  for (int m = 0; m < 2; ++m) {
    int gcol = bn0 + wc + la;
    #pragma unroll
    for (int j = 0; j < 4; ++j) {
      int r = brow + wr + m * 16 + lb * 4 + j;
      Cf[(size_t)r * 1024 + gcol] = acc[m][0][j];
    }
  }
}

// ---------------- per-chunk KV sums (MFMA): S[c][h][m][d] (bf16) = sum_i K[i][d]*V[i][m] ----------------
__global__ __launch_bounds__(256) void chunk_kv_k(const u16* __restrict__ Kb, const u16* __restrict__ Vb,
                                                  u16* __restrict__ S, float* __restrict__ ksum) {
  int c = blockIdx.x, h = blockIdx.y;
  __shared__ __align__(16) u16 Kt[64][72];   // Kt[d][i] = K[i][d]
  __shared__ __align__(16) u16 Vt[64][72];   // Vt[m][i] = V[i][m]
  const int t = threadIdx.x;
  const int lane = t & 63, w = t >> 6;
  const int la = lane & 15, lb = lane >> 4;
  const size_t chb = (size_t)(c * 16 + h);
  #pragma unroll
  for (int i = 0; i < 2; ++i) {
    int r = i * 32 + (t >> 3), col = (t & 7) * 8;
    size_t g = (size_t)(c * 64 + r) * 1024 + h * 64 + col;
    u32x4 kk = *(const u32x4*)(&Kb[g]);
    u32x4 vv = *(const u32x4*)(&Vb[g]);
    #pragma unroll
    for (int j2 = 0; j2 < 4; ++j2) {       // constant index -> stays in registers
      u32 kw = kk[j2], vw = vv[j2];
      Kt[col + 2*j2    ][r] = (u16)(kw & 0xffffu);
      Kt[col + 2*j2 + 1][r] = (u16)(kw >> 16);
      Vt[col + 2*j2    ][r] = (u16)(vw & 0xffffu);
      Vt[col + 2*j2 + 1][r] = (u16)(vw >> 16);
    }
  }
  __syncthreads();
  {
    const int wrm = (w >> 1) * 32, wcd = (w & 1) * 32;
    f32x4 a2[2][2];
    #pragma unroll
    for (int m = 0; m < 2; ++m)
      #pragma unroll
      for (int n = 0; n < 2; ++n) a2[m][n] = (f32x4){0.f, 0.f, 0.f, 0.f};
    #pragma unroll
    for (int ks = 0; ks < 2; ++ks) {
      bf16x8 af[2], bff[2];
      #pragma unroll
      for (int m = 0; m < 2; ++m) af[m] = __builtin_bit_cast(bf16x8, *(const u32x4*)(&Vt[wrm + m*16 + la][ks*32 + lb*8]));
      #pragma unroll
      for (int n = 0; n < 2; ++n) bff[n] = __builtin_bit_cast(bf16x8, *(const u32x4*)(&Kt[wcd + n*16 + la][ks*32 + lb*8]));
      #pragma unroll
      for (int m = 0; m < 2; ++m)
        #pragma unroll
        for (int n = 0; n < 2; ++n)
          a2[m][n] = __builtin_amdgcn_mfma_f32_16x16x32_bf16(af[m], bff[n], a2[m][n], 0, 0, 0);
    }
    #pragma unroll
    for (int m = 0; m < 2; ++m)
      #pragma unroll
      for (int n = 0; n < 2; ++n) {
        int dcol = wcd + n * 16 + la;
        #pragma unroll
        for (int j = 0; j < 4; ++j) {
          int mrow = wrm + m * 16 + lb * 4 + j;
          S[(chb << 12) + (size_t)mrow * 64 + dcol] = f2bf(a2[m][n][j]);
        }
      }
  }
  if (t < 64) {
    float s = 0.f;
    #pragma unroll
    for (int i8 = 0; i8 < 8; ++i8) {
      u32x4 rowv = *(const u32x4*)(&Kt[t][i8 * 8]);
      #pragma unroll
      for (int j = 0; j < 4; ++j) {
        u32 wrd = rowv[j];
        s += bf2f((u16)(wrd & 0xffffu)) + bf2f((u16)(wrd >> 16));
      }
    }
    ksum[chb * 64 + t] = s;
  }
}

// ---------------- exclusive chunk prefix: Pt[c][h][m][d] (bf16), kp[c][h][d] (f32) ----------------
__global__ __launch_bounds__(256) void prefix_k(const u16* __restrict__ S, const float* __restrict__ ksum,
                                                u16* __restrict__ Pt, float* __restrict__ kp) {
  int idx = blockIdx.x * 256 + threadIdx.x;   // over 16*4096
  int h = idx >> 12, e = idx & 4095;
  float run = 0.f;
  #pragma unroll
  for (int c = 0; c < 32; ++c) {
    size_t cb = (size_t)(c * 16 + h) << 12;
    Pt[cb + e] = f2bf(run);
    run += bf2f(S[cb + e]);
  }
  if (idx < 1024) {
    int hh = idx >> 6, dd = idx & 63;
    float r2 = 0.f;
    #pragma unroll
    for (int c = 0; c < 32; ++c) {
      kp[(c * 16 + hh) * 64 + dd] = r2;
      r2 += ksum[(c * 16 + hh) * 64 + dd];
    }
  }
}

// ---------------- per-chunk output: num = tril(QK^T)@V + Q@P ; den = rowsum + Q.kp ----------------
__global__ __launch_bounds__(256) void chunk_out_k(const u16* __restrict__ Qb, const u16* __restrict__ Kb,
    const u16* __restrict__ Vb, const u16* __restrict__ Pt, const float* __restrict__ kp,
    u16* __restrict__ attnb)
{
  int c = blockIdx.x, h = blockIdx.y;
  __shared__ __align__(16) u16 Qs[64][72];
  __shared__ __align__(16) u16 Ks2[64][72];
  __shared__ __align__(16) u16 Vt[64][72];   // Vt[m][i] = V[i][m]
  __shared__ __align__(16) u16 Pts[64][72];  // Pts[m][d]
  __shared__ __align__(16) u16 Am[64][72];   // masked QK^T, bf16
  __shared__ float den_s[64];
  __shared__ float kps[64];
  const int t = threadIdx.x;
  const int lane = t & 63, w = t >> 6;
  const int la = lane & 15, lb = lane >> 4;
  #pragma unroll
  for (int i = 0; i < 2; ++i) {
    int r = i * 32 + (t >> 3), col = (t & 7) * 8;
    size_t g = (size_t)(c * 64 + r) * 1024 + h * 64 + col;
    *(u32x4*)(&Qs[r][col]) = *(const u32x4*)(&Qb[g]);
    *(u32x4*)(&Ks2[r][col]) = *(const u32x4*)(&Kb[g]);
    u32x4 vv = *(const u32x4*)(&Vb[g]);
    #pragma unroll
    for (int j2 = 0; j2 < 4; ++j2) {        // constant index -> registers, not scratch
      u32 vw = vv[j2];
      Vt[col + 2*j2    ][r] = (u16)(vw & 0xffffu);
      Vt[col + 2*j2 + 1][r] = (u16)(vw >> 16);
    }
    *(u32x4*)(&Pts[r][col]) = *(const u32x4*)(&Pt[(((size_t)(c * 16 + h)) << 12) + (size_t)r * 64 + col]);
  }
  if (t < 64) kps[t] = kp[(c * 16 + h) * 64 + t];
  __syncthreads();
  // phase A: Am = tril(Q @ K^T)
  {
    const int wr = (w >> 1) * 32, wc = (w & 1) * 32;
    f32x4 acc[2][2];
    #pragma unroll
    for (int m = 0; m < 2; ++m)
      #pragma unroll
      for (int n = 0; n < 2; ++n) acc[m][n] = (f32x4){0.f, 0.f, 0.f, 0.f};
    #pragma unroll
    for (int ks = 0; ks < 2; ++ks) {
      bf16x8 af[2], bff[2];
      #pragma unroll
      for (int m = 0; m < 2; ++m) af[m] = __builtin_bit_cast(bf16x8, *(const u32x4*)(&Qs[wr + m*16 + la][ks*32 + lb*8]));
      #pragma unroll
      for (int n = 0; n < 2; ++n) bff[n] = __builtin_bit_cast(bf16x8, *(const u32x4*)(&Ks2[wc + n*16 + la][ks*32 + lb*8]));
      #pragma unroll
      for (int m = 0; m < 2; ++m)
        #pragma unroll
        for (int n = 0; n < 2; ++n)
          acc[m][n] = __builtin_amdgcn_mfma_f32_16x16x32_bf16(af[m], bff[n], acc[m][n], 0, 0, 0);
    }
    #pragma unroll
    for (int m = 0; m < 2; ++m)
      #pragma unroll
      for (int n = 0; n < 2; ++n) {
        int col = wc + n * 16 + la;
        #pragma unroll
        for (int j = 0; j < 4; ++j) {
          int r = wr + m * 16 + lb * 4 + j;
          Am[r][col] = f2bf(col <= r ? acc[m][n][j] : 0.f);
        }
      }
  }
  __syncthreads();
  // denominator: den[l] = sum_i Am[l][i] + Q[l].kp  (4 lanes per row, each 16 terms)
  {
    int l = t >> 2, q = t & 3;
    float s = 0.f;
    #pragma unroll
    for (int i = 0; i < 16; ++i) s += bf2f(Am[l][q * 16 + i]);
    #pragma unroll
    for (int d = 0; d < 16; ++d) s += bf2f(Qs[l][q * 16 + d]) * kps[q * 16 + d];
    s += __shfl_xor(s, 1);
    s += __shfl_xor(s, 2);
    if (q == 0) den_s[l] = s;
  }
  __syncthreads();
  // phase B: num = Am @ V + Q @ P ; write attn = num/(den+eps)
  {
    const int row0 = w * 16;
    f32x4 acc[4];
    #pragma unroll
    for (int n = 0; n < 4; ++n) acc[n] = (f32x4){0.f, 0.f, 0.f, 0.f};
    #pragma unroll
    for (int ks = 0; ks < 2; ++ks) {
      bf16x8 a1 = __builtin_bit_cast(bf16x8, *(const u32x4*)(&Am[row0 + la][ks*32 + lb*8]));
      bf16x8 a2 = __builtin_bit_cast(bf16x8, *(const u32x4*)(&Qs[row0 + la][ks*32 + lb*8]));
      #pragma unroll
      for (int n = 0; n < 4; ++n) {
        bf16x8 b1 = __builtin_bit_cast(bf16x8, *(const u32x4*)(&Vt[n*16 + la][ks*32 + lb*8]));
        acc[n] = __builtin_amdgcn_mfma_f32_16x16x32_bf16(a1, b1, acc[n], 0, 0, 0);
        bf16x8 b2 = __builtin_bit_cast(bf16x8, *(const u32x4*)(&Pts[n*16 + la][ks*32 + lb*8]));
        acc[n] = __builtin_amdgcn_mfma_f32_16x16x32_bf16(a2, b2, acc[n], 0, 0, 0);
      }
    }
    #pragma unroll
    for (int n = 0; n < 4; ++n) {
      int col = n * 16 + la;
      #pragma unroll
      for (int j = 0; j < 4; ++j) {
        int r = row0 + lb * 4 + j;
        float v = acc[n][j] / (den_s[r] + 1e-6f);
        attnb[(size_t)(c * 64 + r) * 1024 + h * 64 + col] = f2bf(v);
      }
    }
  }
}

extern "C" void kernel_launch(void* const* d_in, const int* in_sizes, int n_in,
                              void* d_out, int out_size, void* d_ws, size_t ws_size,
                              hipStream_t stream) {
  const float* x  = (const float*)d_in[0];
  const float* wq = (const float*)d_in[1];
  const float* wk = (const float*)d_in[2];
  const float* wv = (const float*)d_in[3];
  const float* wo = (const float*)d_in[4];
  float* out = (float*)d_out;
  char* ws = (char*)d_ws;
  const size_t MB = 1024 * 1024;
  u16*   xb    = (u16*)(ws + 0 * MB);         // 4 MB
  u16*   wqt   = (u16*)(ws + 4 * MB);         // 2 MB  (wqt|wkt|wvt contiguous = fused B, N=3072)
  u16*   wkt   = (u16*)(ws + 6 * MB);         // 2 MB
  u16*   wvt   = (u16*)(ws + 8 * MB);         // 2 MB
  u16*   wot   = (u16*)(ws + 10 * MB);        // 2 MB
  u16*   Qb    = (u16*)(ws + 12 * MB);        // 4 MB
  u16*   Kb    = (u16*)(ws + 16 * MB);        // 4 MB
  u16*   Vb    = (u16*)(ws + 20 * MB);        // 4 MB
  u16*   S     = (u16*)(ws + 24 * MB);        // 4 MB  (bf16: 32 c x 16 h x 64 m x 64 d)
  u16*   Pt    = (u16*)(ws + 32 * MB);        // 4 MB
  float* ksum  = (float*)(ws + 36 * MB);      // 128 KB
  float* kp    = (float*)(ws + 36 * MB + 128 * 1024); // 128 KB
  u16*   attnb = (u16*)(ws + 37 * MB);        // 4 MB
  float* trig  = (float*)(ws + 41 * MB);      // 512 KB

  prep_k<<<1024 + 256 + 4096, 256, 0, stream>>>(x, wq, wk, wv, wo, xb, wqt, wkt, wvt, wot, trig);
  // qkv fused over N=3072: 128x96 tiles, 6 waves of 64x32 -> 512 blocks (2/CU, 56KB LDS)
  gemm_qkv<<<512, 384, 0, stream>>>(xb, wqt, Qb, Kb, Vb, trig);
  chunk_kv_k<<<dim3(32, 16), 256, 0, stream>>>(Kb, Vb, S, ksum);
  prefix_k<<<256, 256, 0, stream>>>(S, ksum, Pt, kp);
  chunk_out_k<<<dim3(32, 16), 256, 0, stream>>>(Qb, Kb, Vb, Pt, kp, attnb);
  // output projection: 128x32 tiles, 8 waves -> 512 blocks (2/CU, 40KB LDS)
  gemm_wo<<<512, 512, 0, stream>>>(attnb, wot, out);
}

// Round 17
// 58.434 us; speedup vs baseline: 1.1673x; 1.1673x over previous
//
#include <hip/hip_runtime.h>

typedef unsigned short u16;
typedef unsigned int u32;
typedef __attribute__((ext_vector_type(8))) __bf16 bf16x8;
typedef __attribute__((ext_vector_type(4))) float f32x4;
typedef __attribute__((ext_vector_type(4))) u32 u32x4;

__device__ __forceinline__ u16 f2bf(float f) {
  u32 u = __builtin_bit_cast(u32, f);
  u = (u + 0x7fffu + ((u >> 16) & 1u)) >> 16;
  return (u16)u;
}
__device__ __forceinline__ float bf2f(u16 h) {
  return __builtin_bit_cast(float, (u32)h << 16);
}
// async global->LDS, 16B per lane; lds dest is wave-uniform base + lane*16
__device__ __forceinline__ void async16(const void* g, void* l) {
  __builtin_amdgcn_global_load_lds((const __attribute__((address_space(1))) u32*)g,
                                   (__attribute__((address_space(3))) u32*)l, 16, 0, 0);
}
template<int N> __device__ __forceinline__ void wait_vm() {
  if constexpr (N == 0) asm volatile("s_waitcnt vmcnt(0)" ::: "memory");
  else if constexpr (N == 2) asm volatile("s_waitcnt vmcnt(2)" ::: "memory");
  else if constexpr (N == 3) asm volatile("s_waitcnt vmcnt(3)" ::: "memory");
  else if constexpr (N == 4) asm volatile("s_waitcnt vmcnt(4)" ::: "memory");
}

// ---------------- merged prep: x->bf16 | trig table | weight transpose+bf16 ----------------
__global__ __launch_bounds__(256) void prep_k(const float* __restrict__ x,
    const float* __restrict__ wq, const float* __restrict__ wk,
    const float* __restrict__ wv, const float* __restrict__ wo,
    u16* __restrict__ xb, u16* __restrict__ wqt, u16* __restrict__ wkt,
    u16* __restrict__ wvt, u16* __restrict__ wot, float* __restrict__ trig) {
  __shared__ float tile[32][33];
  int b = blockIdx.x, t = threadIdx.x;
  if (b < 1024) {            // conv x: 2048*1024 elems, 8/thread
    int i = (b * 256 + t) * 8;
    u16 tmp[8];
    #pragma unroll
    for (int j = 0; j < 8; ++j) tmp[j] = f2bf(x[i + j]);
    *(u32x4*)(&xb[i]) = *(u32x4*)tmp;
  } else if (b < 1280) {     // trig: idx = l*32+j over 2048*32
    int idx = (b - 1024) * 256 + t;
    int l = idx >> 5, j = idx & 31;
    float invf = powf(10000.0f, -(float)j * (1.0f / 32.0f));
    float ang = (float)l * invf;
    trig[idx * 2 + 0] = cosf(ang);
    trig[idx * 2 + 1] = sinf(ang);
  } else {                   // weight transpose: 4 mats x 1024 tiles of 32x32
    int bb = b - 1280;
    int z = bb >> 10, tt = bb & 1023;
    const float* w = z == 0 ? wq : z == 1 ? wk : z == 2 ? wv : wo;
    u16* o = z == 0 ? wqt : z == 1 ? wkt : z == 2 ? wvt : wot;
    int tx = t & 31, ty = t >> 5;
    int n0 = (tt & 31) * 32, k0 = (tt >> 5) * 32;
    #pragma unroll
    for (int j = 0; j < 4; ++j) tile[ty + j*8][tx] = w[(size_t)(k0 + ty + j*8) * 1024 + n0 + tx];
    __syncthreads();
    #pragma unroll
    for (int j = 0; j < 4; ++j) o[(size_t)(n0 + ty + j*8) * 1024 + k0 + tx] = f2bf(tile[tx][ty + j*8]);
  }
}

// ---------------- qkv GEMM: 128x96 tile, BK=64, 8 waves (512 thr), 2-buf counted-vmcnt ----
// [R11 best] C cols span Wq|Wk|Wv (N=3072); rope/relu fused for z<2. Supertile XCD
// swizzle: per XCD 8bx x 8by -> 1.5MB B + 2MB A <= 4MB L2.
__global__ __launch_bounds__(512) void gemm_qkv(
    const u16* __restrict__ A, const u16* __restrict__ B,
    u16* __restrict__ Cq, u16* __restrict__ Ck, u16* __restrict__ Cv,
    const float* __restrict__ trig)
{
  constexpr int BM = 128, BN = 96, K = 1024, NT = 16;
  constexpr int LDSZ = (BM + BN) * 64;        // 28KB per buffer
  __shared__ __align__(16) u16 lds[2][LDSZ];
  const int t = threadIdx.x, lane = t & 63, w = t >> 6;   // w in 0..7
  const int la = lane & 15, lb = lane >> 4;
  const int hw = blockIdx.x;
  const int xcd = hw & 7, q = hw >> 3;
  const int bx = (xcd & 3) * 8 + (q & 7);     // 32 bx
  const int by = (xcd >> 2) * 8 + (q >> 3);   // 16 by
  const int brow = by * BM, bn0 = bx * BN;
  const u16* Bp = B + (size_t)bn0 * K;
  const int wr = (w >> 1) * 32, wc = (w & 1) * 48;   // wave tile 32x48 (4x2 partition)
  f32x4 acc[2][3];
  #pragma unroll
  for (int m = 0; m < 2; ++m)
    #pragma unroll
    for (int n = 0; n < 3; ++n) acc[m][n] = (f32x4){0.f, 0.f, 0.f, 0.f};
  const int srow8 = lane >> 3;                // row within 8-row chunk
  const int sw8 = (((lane & 7) ^ srow8) << 3);

  // staging: A = 16 chunks (8r x 64c = 1KB), B = 12 chunks.
  // wave w: A chunks {w, w+8}; B chunk {w}; waves 0-3 also B chunk {8+w}.
  auto stage = [&](int buf, int kt) {
    const int k0 = kt * 64;
    async16(&A[(size_t)(brow + w * 8 + srow8) * K + k0 + sw8], &lds[buf][w * 512]);
    async16(&A[(size_t)(brow + (w + 8) * 8 + srow8) * K + k0 + sw8], &lds[buf][(w + 8) * 512]);
    async16(&Bp[(size_t)(w * 8 + srow8) * K + k0 + sw8], &lds[buf][BM * 64 + w * 512]);
    if (w < 4)
      async16(&Bp[(size_t)((8 + w) * 8 + srow8) * K + k0 + sw8], &lds[buf][BM * 64 + (8 + w) * 512]);
  };
  auto wait_stage = [&](bool last) {   // keep 1 stage (4 or 3 loads) in flight
    if (last) { wait_vm<0>(); }
    else if (w < 4) { wait_vm<4>(); }
    else { wait_vm<3>(); }
  };
  auto compute = [&](int buf) {
    __builtin_amdgcn_s_setprio(1);
    #pragma unroll
    for (int ks = 0; ks < 2; ++ks) {
      bf16x8 af[2], bff[3];
      const int slot = ks * 4 + lb;
      #pragma unroll
      for (int m = 0; m < 2; ++m) {
        int row = wr + m * 16 + la;
        af[m] = __builtin_bit_cast(bf16x8,
            *(const u32x4*)(&lds[buf][row * 64 + ((slot ^ (row & 7)) << 3)]));
      }
      #pragma unroll
      for (int n = 0; n < 3; ++n) {
        int row = wc + n * 16 + la;
        bff[n] = __builtin_bit_cast(bf16x8,
            *(const u32x4*)(&lds[buf][BM * 64 + row * 64 + ((slot ^ (row & 7)) << 3)]));
      }
      #pragma unroll
      for (int m = 0; m < 2; ++m)
        #pragma unroll
        for (int n = 0; n < 3; ++n)
          acc[m][n] = __builtin_amdgcn_mfma_f32_16x16x32_bf16(af[m], bff[n], acc[m][n], 0, 0, 0);
    }
    __builtin_amdgcn_s_setprio(0);
  };

  stage(0, 0);
  stage(1, 1);
  for (int kt = 0; kt < NT; ++kt) {
    wait_stage(kt == NT - 1);            // stage kt landed; kt+1 stays in flight
    __builtin_amdgcn_s_barrier();
    compute(kt & 1);
    __builtin_amdgcn_s_barrier();        // all waves done reading buf kt&1
    if (kt + 2 < NT) stage(kt & 1, kt + 2);
  }

  // C/D layout: row = (lane>>4)*4 + j, col = lane&15  [m89]; per-n z select
  #pragma unroll
  for (int m = 0; m < 2; ++m) {
    #pragma unroll
    for (int n = 0; n < 3; ++n) {
      int gcol = bn0 + wc + n * 16 + la;
      int z = gcol >> 10, colz = gcol & 1023;
      u16* C = z == 0 ? Cq : z == 1 ? Ck : Cv;
      bool do_rope = z < 2;
      int jj = (colz & 63) >> 1;
      bool odd = colz & 1;
      #pragma unroll
      for (int j = 0; j < 4; ++j) {
        int r = brow + wr + m * 16 + lb * 4 + j;
        float v = acc[m][n][j];
        float p = __shfl_xor(v, 1);   // pair partner (col ^ 1) — uniform exec
        if (do_rope) {
          float2 t2 = *(const float2*)(&trig[((size_t)r * 32 + jj) * 2]);
          v = odd ? (p * t2.y + v * t2.x) : (v * t2.x - p * t2.y);
          v = fmaxf(v, 0.f);
        }
        C[(size_t)r * 1024 + colz] = f2bf(v);
      }
    }
  }
}

// ---------------- wo GEMM: 128x32 tile, BK=64, 8 waves (512 thr), 2-buf counted-vmcnt ----
__global__ __launch_bounds__(512) void gemm_wo(
    const u16* __restrict__ A, const u16* __restrict__ B, float* __restrict__ Cf)
{
  constexpr int BM = 128, BN = 32, K = 1024, NT = 16;
  constexpr int LDSZ = (BM + BN) * 64;        // 20KB per buffer
  __shared__ __align__(16) u16 lds[2][LDSZ];
  const int t = threadIdx.x, lane = t & 63, w = t >> 6;   // w in 0..7
  const int la = lane & 15, lb = lane >> 4;
  const int hw = blockIdx.x;
  const int xcd = hw & 7, q = hw >> 3;        // q in [0,64)
  const int bx = (xcd & 1) * 16 + (q & 15);   // 32 bx over N=1024
  const int by = (xcd >> 1) * 4 + (q >> 4);   // 16 by over M=2048
  const int brow = by * BM, bn0 = bx * BN;
  const u16* Bp = B + (size_t)bn0 * K;
  const int wr = (w >> 1) * 32, wc = (w & 1) * 16;   // wave tile 32x16 (4x2 partition)
  f32x4 acc[2][1];
  #pragma unroll
  for (int m = 0; m < 2; ++m) acc[m][0] = (f32x4){0.f, 0.f, 0.f, 0.f};
  const int srow8 = lane >> 3;
  const int sw8 = (((lane & 7) ^ srow8) << 3);

  // staging: A = 16 chunks, B = 4 chunks. wave w: A {w, w+8}; waves 0-3: B {w}.
  auto stage = [&](int buf, int kt) {
    const int k0 = kt * 64;
    async16(&A[(size_t)(brow + w * 8 + srow8) * K + k0 + sw8], &lds[buf][w * 512]);
    async16(&A[(size_t)(brow + (w + 8) * 8 + srow8) * K + k0 + sw8], &lds[buf][(w + 8) * 512]);
    if (w < 4)
      async16(&Bp[(size_t)(w * 8 + srow8) * K + k0 + sw8], &lds[buf][BM * 64 + w * 512]);
  };
  auto wait_stage = [&](bool last) {
    if (last) { wait_vm<0>(); }
    else if (w < 4) { wait_vm<3>(); }
    else { wait_vm<2>(); }
  };
  auto compute = [&](int buf) {
    __builtin_amdgcn_s_setprio(1);
    #pragma unroll
    for (int ks = 0; ks < 2; ++ks) {
      bf16x8 af[2], bf1;
      const int slot = ks * 4 + lb;
      #pragma unroll
      for (int m = 0; m < 2; ++m) {
        int row = wr + m * 16 + la;
        af[m] = __builtin_bit_cast(bf16x8,
            *(const u32x4*)(&lds[buf][row * 64 + ((slot ^ (row & 7)) << 3)]));
      }
      {
        int row = wc + la;
        bf1 = __builtin_bit_cast(bf16x8,
            *(const u32x4*)(&lds[buf][BM * 64 + row * 64 + ((slot ^ (row & 7)) << 3)]));
      }
      #pragma unroll
      for (int m = 0; m < 2; ++m)
        acc[m][0] = __builtin_amdgcn_mfma_f32_16x16x32_bf16(af[m], bf1, acc[m][0], 0, 0, 0);
    }
    __builtin_amdgcn_s_setprio(0);
  };

  stage(0, 0);
  stage(1, 1);
  for (int kt = 0; kt < NT; ++kt) {
    wait_stage(kt == NT - 1);
    __builtin_amdgcn_s_barrier();
    compute(kt & 1);
    __builtin_amdgcn_s_barrier();
    if (kt + 2 < NT) stage(kt & 1, kt + 2);
  }

  #pragma unroll
  for (int m = 0; m < 2; ++m) {
    int gcol = bn0 + wc + la;
    #pragma unroll
    for (int j = 0; j < 4; ++j) {
      int r = brow + wr + m * 16 + lb * 4 + j;
      Cf[(size_t)r * 1024 + gcol] = acc[m][0][j];
    }
  }
}

// ---------------- per-chunk KV sums (MFMA): S[c][h][m][d] (bf16) = sum_i K[i][d]*V[i][m] ----------------
// Transpose via CONSTANT-index vector extraction (no runtime-indexed register arrays -> no scratch).
__global__ __launch_bounds__(256) void chunk_kv_k(const u16* __restrict__ Kb, const u16* __restrict__ Vb,
                                                  u16* __restrict__ S, float* __restrict__ ksum) {
  int c = blockIdx.x, h = blockIdx.y;
  __shared__ __align__(16) u16 Kt[64][72];   // Kt[d][i] = K[i][d]
  __shared__ __align__(16) u16 Vt[64][72];   // Vt[m][i] = V[i][m]
  const int t = threadIdx.x;
  const int lane = t & 63, w = t >> 6;
  const int la = lane & 15, lb = lane >> 4;
  const size_t chb = (size_t)(c * 16 + h);
  #pragma unroll
  for (int i = 0; i < 2; ++i) {
    int r = i * 32 + (t >> 3), col = (t & 7) * 8;
    size_t g = (size_t)(c * 64 + r) * 1024 + h * 64 + col;
    u32x4 kk = *(const u32x4*)(&Kb[g]);
    u32x4 vv = *(const u32x4*)(&Vb[g]);
    #pragma unroll
    for (int j2 = 0; j2 < 4; ++j2) {       // constant index -> stays in registers
      u32 kw = kk[j2], vw = vv[j2];
      Kt[col + 2*j2    ][r] = (u16)(kw & 0xffffu);
      Kt[col + 2*j2 + 1][r] = (u16)(kw >> 16);
      Vt[col + 2*j2    ][r] = (u16)(vw & 0xffffu);
      Vt[col + 2*j2 + 1][r] = (u16)(vw >> 16);
    }
  }
  __syncthreads();
  {
    const int wrm = (w >> 1) * 32, wcd = (w & 1) * 32;
    f32x4 a2[2][2];
    #pragma unroll
    for (int m = 0; m < 2; ++m)
      #pragma unroll
      for (int n = 0; n < 2; ++n) a2[m][n] = (f32x4){0.f, 0.f, 0.f, 0.f};
    #pragma unroll
    for (int ks = 0; ks < 2; ++ks) {
      bf16x8 af[2], bff[2];
      #pragma unroll
      for (int m = 0; m < 2; ++m) af[m] = __builtin_bit_cast(bf16x8, *(const u32x4*)(&Vt[wrm + m*16 + la][ks*32 + lb*8]));
      #pragma unroll
      for (int n = 0; n < 2; ++n) bff[n] = __builtin_bit_cast(bf16x8, *(const u32x4*)(&Kt[wcd + n*16 + la][ks*32 + lb*8]));
      #pragma unroll
      for (int m = 0; m < 2; ++m)
        #pragma unroll
        for (int n = 0; n < 2; ++n)
          a2[m][n] = __builtin_amdgcn_mfma_f32_16x16x32_bf16(af[m], bff[n], a2[m][n], 0, 0, 0);
    }
    #pragma unroll
    for (int m = 0; m < 2; ++m)
      #pragma unroll
      for (int n = 0; n < 2; ++n) {
        int dcol = wcd + n * 16 + la;
        #pragma unroll
        for (int j = 0; j < 4; ++j) {
          int mrow = wrm + m * 16 + lb * 4 + j;
          S[(chb << 12) + (size_t)mrow * 64 + dcol] = f2bf(a2[m][n][j]);
        }
      }
  }
  if (t < 64) {
    float s = 0.f;
    #pragma unroll
    for (int i8 = 0; i8 < 8; ++i8) {
      u32x4 rowv = *(const u32x4*)(&Kt[t][i8 * 8]);
      #pragma unroll
      for (int j = 0; j < 4; ++j) {
        u32 wrd = rowv[j];
        s += bf2f((u16)(wrd & 0xffffu)) + bf2f((u16)(wrd >> 16));
      }
    }
    ksum[chb * 64 + t] = s;
  }
}

// ---------------- exclusive chunk prefix: Pt[c][h][m][d] (bf16), kp[c][h][d] (f32) ----------------
__global__ __launch_bounds__(256) void prefix_k(const u16* __restrict__ S, const float* __restrict__ ksum,
                                                u16* __restrict__ Pt, float* __restrict__ kp) {
  int idx = blockIdx.x * 256 + threadIdx.x;   // over 16*4096
  int h = idx >> 12, e = idx & 4095;
  float run = 0.f;
  #pragma unroll
  for (int c = 0; c < 32; ++c) {
    size_t cb = (size_t)(c * 16 + h) << 12;
    Pt[cb + e] = f2bf(run);
    run += bf2f(S[cb + e]);
  }
  if (idx < 1024) {
    int hh = idx >> 6, dd = idx & 63;
    float r2 = 0.f;
    #pragma unroll
    for (int c = 0; c < 32; ++c) {
      kp[(c * 16 + hh) * 64 + dd] = r2;
      r2 += ksum[(c * 16 + hh) * 64 + dd];
    }
  }
}

// ---------------- per-chunk output: num = tril(QK^T)@V + Q@P ; den = rowsum + Q.kp ----------------
// V-transpose via CONSTANT-index vector extraction (no scratch).
__global__ __launch_bounds__(256) void chunk_out_k(const u16* __restrict__ Qb, const u16* __restrict__ Kb,
    const u16* __restrict__ Vb, const u16* __restrict__ Pt, const float* __restrict__ kp,
    u16* __restrict__ attnb)
{
  int c = blockIdx.x, h = blockIdx.y;
  __shared__ __align__(16) u16 Qs[64][72];
  __shared__ __align__(16) u16 Ks2[64][72];
  __shared__ __align__(16) u16 Vt[64][72];   // Vt[m][i] = V[i][m]
  __shared__ __align__(16) u16 Pts[64][72];  // Pts[m][d]
  __shared__ __align__(16) u16 Am[64][72];   // masked QK^T, bf16
  __shared__ float den_s[64];
  __shared__ float kps[64];
  const int t = threadIdx.x;
  const int lane = t & 63, w = t >> 6;
  const int la = lane & 15, lb = lane >> 4;
  #pragma unroll
  for (int i = 0; i < 2; ++i) {
    int r = i * 32 + (t >> 3), col = (t & 7) * 8;
    size_t g = (size_t)(c * 64 + r) * 1024 + h * 64 + col;
    *(u32x4*)(&Qs[r][col]) = *(const u32x4*)(&Qb[g]);
    *(u32x4*)(&Ks2[r][col]) = *(const u32x4*)(&Kb[g]);
    u32x4 vv = *(const u32x4*)(&Vb[g]);
    #pragma unroll
    for (int j2 = 0; j2 < 4; ++j2) {        // constant index -> registers, not scratch
      u32 vw = vv[j2];
      Vt[col + 2*j2    ][r] = (u16)(vw & 0xffffu);
      Vt[col + 2*j2 + 1][r] = (u16)(vw >> 16);
    }
    *(u32x4*)(&Pts[r][col]) = *(const u32x4*)(&Pt[(((size_t)(c * 16 + h)) << 12) + (size_t)r * 64 + col]);
  }
  if (t < 64) kps[t] = kp[(c * 16 + h) * 64 + t];
  __syncthreads();
  // phase A: Am = tril(Q @ K^T)
  {
    const int wr = (w >> 1) * 32, wc = (w & 1) * 32;
    f32x4 acc[2][2];
    #pragma unroll
    for (int m = 0; m < 2; ++m)
      #pragma unroll
      for (int n = 0; n < 2; ++n) acc[m][n] = (f32x4){0.f, 0.f, 0.f, 0.f};
    #pragma unroll
    for (int ks = 0; ks < 2; ++ks) {
      bf16x8 af[2], bff[2];
      #pragma unroll
      for (int m = 0; m < 2; ++m) af[m] = __builtin_bit_cast(bf16x8, *(const u32x4*)(&Qs[wr + m*16 + la][ks*32 + lb*8]));
      #pragma unroll
      for (int n = 0; n < 2; ++n) bff[n] = __builtin_bit_cast(bf16x8, *(const u32x4*)(&Ks2[wc + n*16 + la][ks*32 + lb*8]));
      #pragma unroll
      for (int m = 0; m < 2; ++m)
        #pragma unroll
        for (int n = 0; n < 2; ++n)
          acc[m][n] = __builtin_amdgcn_mfma_f32_16x16x32_bf16(af[m], bff[n], acc[m][n], 0, 0, 0);
    }
    #pragma unroll
    for (int m = 0; m < 2; ++m)
      #pragma unroll
      for (int n = 0; n < 2; ++n) {
        int col = wc + n * 16 + la;
        #pragma unroll
        for (int j = 0; j < 4; ++j) {
          int r = wr + m * 16 + lb * 4 + j;
          Am[r][col] = f2bf(col <= r ? acc[m][n][j] : 0.f);
        }
      }
  }
  __syncthreads();
  // denominator: den[l] = sum_i Am[l][i] + Q[l].kp  (4 lanes per row, each 16 terms)
  {
    int l = t >> 2, q = t & 3;
    float s = 0.f;
    #pragma unroll
    for (int i = 0; i < 16; ++i) s += bf2f(Am[l][q * 16 + i]);
    #pragma unroll
    for (int d = 0; d < 16; ++d) s += bf2f(Qs[l][q * 16 + d]) * kps[q * 16 + d];
    s += __shfl_xor(s, 1);
    s += __shfl_xor(s, 2);
    if (q == 0) den_s[l] = s;
  }
  __syncthreads();
  // phase B: num = Am @ V + Q @ P ; write attn = num/(den+eps)
  {
    const int row0 = w * 16;
    f32x4 acc[4];
    #pragma unroll
    for (int n = 0; n < 4; ++n) acc[n] = (f32x4){0.f, 0.f, 0.f, 0.f};
    #pragma unroll
    for (int ks = 0; ks < 2; ++ks) {
      bf16x8 a1 = __builtin_bit_cast(bf16x8, *(const u32x4*)(&Am[row0 + la][ks*32 + lb*8]));
      bf16x8 a2 = __builtin_bit_cast(bf16x8, *(const u32x4*)(&Qs[row0 + la][ks*32 + lb*8]));
      #pragma unroll
      for (int n = 0; n < 4; ++n) {
        bf16x8 b1 = __builtin_bit_cast(bf16x8, *(const u32x4*)(&Vt[n*16 + la][ks*32 + lb*8]));
        acc[n] = __builtin_amdgcn_mfma_f32_16x16x32_bf16(a1, b1, acc[n], 0, 0, 0);
        bf16x8 b2 = __builtin_bit_cast(bf16x8, *(const u32x4*)(&Pts[n*16 + la][ks*32 + lb*8]));
        acc[n] = __builtin_amdgcn_mfma_f32_16x16x32_bf16(a2, b2, acc[n], 0, 0, 0);
      }
    }
    #pragma unroll
    for (int n = 0; n < 4; ++n) {
      int col = n * 16 + la;
      #pragma unroll
      for (int j = 0; j < 4; ++j) {
        int r = row0 + lb * 4 + j;
        float v = acc[n][j] / (den_s[r] + 1e-6f);
        attnb[(size_t)(c * 64 + r) * 1024 + h * 64 + col] = f2bf(v);
      }
    }
  }
}

extern "C" void kernel_launch(void* const* d_in, const int* in_sizes, int n_in,
                              void* d_out, int out_size, void* d_ws, size_t ws_size,
                              hipStream_t stream) {
  const float* x  = (const float*)d_in[0];
  const float* wq = (const float*)d_in[1];
  const float* wk = (const float*)d_in[2];
  const float* wv = (const float*)d_in[3];
  const float* wo = (const float*)d_in[4];
  float* out = (float*)d_out;
  char* ws = (char*)d_ws;
  const size_t MB = 1024 * 1024;
  u16*   xb    = (u16*)(ws + 0 * MB);         // 4 MB
  u16*   wqt   = (u16*)(ws + 4 * MB);         // 2 MB  (wqt|wkt|wvt contiguous = fused B, N=3072)
  u16*   wkt   = (u16*)(ws + 6 * MB);         // 2 MB
  u16*   wvt   = (u16*)(ws + 8 * MB);         // 2 MB
  u16*   wot   = (u16*)(ws + 10 * MB);        // 2 MB
  u16*   Qb    = (u16*)(ws + 12 * MB);        // 4 MB
  u16*   Kb    = (u16*)(ws + 16 * MB);        // 4 MB
  u16*   Vb    = (u16*)(ws + 20 * MB);        // 4 MB
  u16*   S     = (u16*)(ws + 24 * MB);        // 4 MB  (bf16: 32 c x 16 h x 64 m x 64 d)
  u16*   Pt    = (u16*)(ws + 32 * MB);        // 4 MB
  float* ksum  = (float*)(ws + 36 * MB);      // 128 KB
  float* kp    = (float*)(ws + 36 * MB + 128 * 1024); // 128 KB
  u16*   attnb = (u16*)(ws + 37 * MB);        // 4 MB
  float* trig  = (float*)(ws + 41 * MB);      // 512 KB

  prep_k<<<1024 + 256 + 4096, 256, 0, stream>>>(x, wq, wk, wv, wo, xb, wqt, wkt, wvt, wot, trig);
  // qkv fused over N=3072: 128x96 tiles, 8 waves -> 512 blocks (2/CU, 56KB LDS)
  gemm_qkv<<<512, 512, 0, stream>>>(xb, wqt, Qb, Kb, Vb, trig);
  chunk_kv_k<<<dim3(32, 16), 256, 0, stream>>>(Kb, Vb, S, ksum);
  prefix_k<<<256, 256, 0, stream>>>(S, ksum, Pt, kp);
  chunk_out_k<<<dim3(32, 16), 256, 0, stream>>>(Qb, Kb, Vb, Pt, kp, attnb);
  // output projection: 128x32 tiles, 8 waves -> 512 blocks (2/CU, 40KB LDS)
  gemm_wo<<<512, 512, 0, stream>>>(attnb, wot, out);
}